// Round 1
// baseline (484.207 us; speedup 1.0000x reference)
//
#include <hip/hip_runtime.h>
#include <hip/hip_bf16.h>
#include <cstdint>

// AttentionGNNLayer: out = relu(segment_sum(relu([h[r],h[s],c]@W1+b1) * sigmoid((h[s]@Wq+bq)·(h[r]@Wk+bk)), r))
//
// Factored: per-node A=h@W1a+b1, B=h@W1b, q=h@Wq+bq, k=h@Wk+bk  (W1a=W1 rows 0..31, W1b=rows 32..63)
// per-edge msg = relu(A[r]+B[s]+c*w1c) * sigmoid(q[s]·k[r]); atomicAdd into agg[r]; relu at end.
// Node features packed bf16: Ak[n][t] = (A_t | k_t<<16), Bq[n][t] = (B_t | q_t<<16) -> 128 B gather per side.

#define NPB 8   // nodes per block (node kernel)
#define EPB 8   // edges per block (edge kernel)

__device__ __forceinline__ float bf16lo(uint32_t u) {
    uint32_t b = (u & 0xFFFFu) << 16;
    float f; __builtin_memcpy(&f, &b, 4); return f;
}
__device__ __forceinline__ float bf16hi(uint32_t u) {
    uint32_t b = u & 0xFFFF0000u;
    float f; __builtin_memcpy(&f, &b, 4); return f;
}
__device__ __forceinline__ uint32_t pack_bf16(float lo, float hi) {
    __hip_bfloat16 l = __float2bfloat16(lo);
    __hip_bfloat16 h = __float2bfloat16(hi);
    uint16_t lb, hb;
    __builtin_memcpy(&lb, &l, 2);
    __builtin_memcpy(&hb, &h, 2);
    return (uint32_t)lb | ((uint32_t)hb << 16);
}

__global__ __launch_bounds__(256) void node_precompute(
    const float* __restrict__ h, const float* __restrict__ W1,
    const float* __restrict__ b1, const float* __restrict__ Wq,
    const float* __restrict__ bq, const float* __restrict__ Wk,
    const float* __restrict__ bk,
    uint32_t* __restrict__ Ak, uint32_t* __restrict__ Bq, int n_nodes)
{
    __shared__ float sW1a[1024], sW1b[1024], sWq[1024], sWk[1024];
    __shared__ float hsh[NPB][32];
    int tid = threadIdx.x;
    for (int i = tid; i < 1024; i += 256) {
        sW1a[i] = W1[i];          // W1 rows 0..31  (receiver part)
        sW1b[i] = W1[1024 + i];   // W1 rows 32..63 (sender part)
        sWq[i]  = Wq[i];
        sWk[i]  = Wk[i];
    }
    __syncthreads();
    int lane = tid & 31;
    int g    = tid >> 5;
    int n    = blockIdx.x * NPB + g;
    if (n < n_nodes) hsh[g][lane] = h[n * 32 + lane];
    __syncthreads();
    if (n >= n_nodes) return;

    float accA = b1[lane];   // fold b1 into A
    float accB = 0.f;
    float accQ = bq[lane];
    float accK = bk[lane];
    #pragma unroll
    for (int j = 0; j < 32; ++j) {
        float hj = hsh[g][j];  // LDS broadcast
        accA = fmaf(hj, sW1a[j * 32 + lane], accA);
        accB = fmaf(hj, sW1b[j * 32 + lane], accB);
        accQ = fmaf(hj, sWq [j * 32 + lane], accQ);
        accK = fmaf(hj, sWk [j * 32 + lane], accK);
    }
    Ak[n * 32 + lane] = pack_bf16(accA, accK);
    Bq[n * 32 + lane] = pack_bf16(accB, accQ);
}

__global__ __launch_bounds__(256) void edge_kernel(
    const uint32_t* __restrict__ Ak, const uint32_t* __restrict__ Bq,
    const int* __restrict__ senders, const int* __restrict__ receivers,
    const float* __restrict__ couplings, const float* __restrict__ W1,
    float* __restrict__ agg, int n_edges, int e_half)
{
    int lane = threadIdx.x & 31;
    int g    = threadIdx.x >> 5;
    int e    = blockIdx.x * EPB + g;
    float w1c = W1[64 * 32 + lane];   // last W1 row (coupling weights); L1-resident
    if (e >= n_edges) return;

    int r = receivers[e];
    int s = senders[e];
    float c = couplings[e < e_half ? e : e - e_half];

    uint32_t ak = Ak[(size_t)r * 32 + lane];  // 128 B coalesced per edge-group
    uint32_t bq = Bq[(size_t)s * 32 + lane];
    float A = bf16lo(ak), k = bf16hi(ak);
    float B = bf16lo(bq), q = bf16hi(bq);

    float msg = fmaxf(fmaf(c, w1c, A + B), 0.f);

    float p = q * k;
    #pragma unroll
    for (int m = 1; m < 32; m <<= 1)
        p += __shfl_xor(p, m, 64);   // masks 1..16 stay within each 32-lane half
    float sig = 1.f / (1.f + __expf(-p));

    atomicAdd(&agg[(size_t)r * 32 + lane], msg * sig);
}

__global__ __launch_bounds__(256) void relu_inplace(float4* __restrict__ out, int n4)
{
    int i = blockIdx.x * blockDim.x + threadIdx.x;
    if (i < n4) {
        float4 v = out[i];
        v.x = fmaxf(v.x, 0.f);
        v.y = fmaxf(v.y, 0.f);
        v.z = fmaxf(v.z, 0.f);
        v.w = fmaxf(v.w, 0.f);
        out[i] = v;
    }
}

extern "C" void kernel_launch(void* const* d_in, const int* in_sizes, int n_in,
                              void* d_out, int out_size, void* d_ws, size_t ws_size,
                              hipStream_t stream)
{
    const float* h         = (const float*)d_in[0];
    const float* couplings = (const float*)d_in[1];
    const float* W1        = (const float*)d_in[2];
    const float* b1        = (const float*)d_in[3];
    const float* Wq        = (const float*)d_in[4];
    const float* bq        = (const float*)d_in[5];
    const float* Wk        = (const float*)d_in[6];
    const float* bk        = (const float*)d_in[7];
    const int*   senders   = (const int*)d_in[8];
    const int*   receivers = (const int*)d_in[9];
    float* out = (float*)d_out;

    int n_nodes = in_sizes[0] / 32;
    int e_half  = in_sizes[1];
    int n_edges = in_sizes[8];

    uint32_t* Ak = (uint32_t*)d_ws;                      // n_nodes*32 u32 = 12.8 MB
    uint32_t* Bq = Ak + (size_t)n_nodes * 32;            // 12.8 MB

    hipMemsetAsync(d_out, 0, (size_t)out_size * sizeof(float), stream);

    node_precompute<<<(n_nodes + NPB - 1) / NPB, 256, 0, stream>>>(
        h, W1, b1, Wq, bq, Wk, bk, Ak, Bq, n_nodes);

    edge_kernel<<<(n_edges + EPB - 1) / EPB, 256, 0, stream>>>(
        Ak, Bq, senders, receivers, couplings, W1, out, n_edges, e_half);

    int n4 = out_size / 4;
    relu_inplace<<<(n4 + 255) / 256, 256, 0, stream>>>((float4*)out, n4);
}